// Round 7
// baseline (28.294 us; speedup 1.0000x reference)
//
#include <hip/hip_runtime.h>
#include <math.h>

#define B_SZ   2048
#define D_SZ   4096
#define TB     16            // batch rows per block
#define NC     16            // d-chunks (256 d per block)
#define DC     256           // d's per block (== blockDim)
#define NBG    (B_SZ / TB)   // 128 batch groups

// ws layout:
//   effp4  : 6*D_SZ float4 = 393216 B   (planar float4; 24 power-basis coefs/d)
//   effb   : D_SZ float4   =  65536 B
//   partial: NC*B_SZ*3 f32 = 393216 B
#define WS_EFFP_BYTES  (6 * D_SZ * 16)
#define WS_EFFB_BYTES  (D_SZ * 16)
#define WS_PART_BYTES  (NC * B_SZ * 3 * 4)

// ---------------------------------------------------------------------------
// Convert B-spline coefs to truncated-power basis:
//   S(u) = p0 + p1 u + p2 u^2 + p3 u^3 + sum_{m=1..4} d_m max(u-m,0)^3
// p* from the cell-0 polynomial; d_m = jump of the u^3 coefficient at knot m.
__global__ __launch_bounds__(256) void precompute_pow(
    const float* __restrict__ coef, const float* __restrict__ sb,
    const float* __restrict__ ssp,  const float* __restrict__ mask,
    float4* __restrict__ effp4, float4* __restrict__ effb)
{
    int d = blockIdx.x * 256 + threadIdx.x;
    if (d >= D_SZ) return;
    float v[24];
    #pragma unroll
    for (int o = 0; o < 3; ++o) {
        float m = mask[d*3 + o];
        float s = ssp[d*3 + o] * m;
        float k[8];
        #pragma unroll
        for (int n = 0; n < 8; ++n) k[n] = coef[(d*3 + o)*8 + n] * s;
        float A3[5];                       // t^3 coef of cell c's local poly
        #pragma unroll
        for (int c = 0; c < 5; ++c)
            A3[c] = (k[c+3] - k[c] + 3.0f*(k[c+1] - k[c+2])) * (1.0f/6.0f);
        v[0*3+o] = (k[0] + 4.0f*k[1] + k[2]) * (1.0f/6.0f);
        v[1*3+o] = (k[2] - k[0]) * 0.5f;
        v[2*3+o] = (k[0] + k[2]) * 0.5f - k[1];
        v[3*3+o] = A3[0];
        v[4*3+o] = A3[1] - A3[0];
        v[5*3+o] = A3[2] - A3[1];
        v[6*3+o] = A3[3] - A3[2];
        v[7*3+o] = A3[4] - A3[3];
    }
    #pragma unroll
    for (int g = 0; g < 6; ++g)
        effp4[(size_t)g * D_SZ + d] =
            make_float4(v[4*g+0], v[4*g+1], v[4*g+2], v[4*g+3]);
    float m0 = mask[d*3+0], m1 = mask[d*3+1], m2 = mask[d*3+2];
    effb[d] = make_float4(sb[d*3+0]*m0, sb[d*3+1]*m1, sb[d*3+2]*m2, 0.0f);
}

// ---------------------------------------------------------------------------
// DPP 16-lane-group suffix sum: lane 15 (mod 16) holds its row's total.
template<int CTRL>
__device__ __forceinline__ float dpp_add(float v) {
    int x = __builtin_amdgcn_update_dpp(0, __float_as_int(v), CTRL, 0xF, 0xF, true);
    return v + __int_as_float(x);
}
__device__ __forceinline__ float group16_sum(float v) {
    v = dpp_add<0x111>(v);   // row_shr:1
    v = dpp_add<0x112>(v);   // row_shr:2
    v = dpp_add<0x114>(v);   // row_shr:4
    v = dpp_add<0x118>(v);   // row_shr:8
    return v;
}

// ---------------------------------------------------------------------------
// Main kernel: pure-VALU main loop (no LDS reads, no selects). Thread owns one
// d with 24 power-basis coefs in registers; 16 b's; immediate DPP reduce.
__global__ __launch_bounds__(256) void kan_main(
    const float* __restrict__ x, const float4* __restrict__ effp4,
    const float4* __restrict__ effb, const float* __restrict__ grid,
    float* __restrict__ partial)
{
    __shared__ float tl[TB * 16 * 3];      // 3 KB: [q][group][o]

    const int tid = threadIdx.x;
    const int bg  = blockIdx.x;            // 0..NBG-1
    const int dc  = blockIdx.y;            // 0..NC-1
    const int d   = dc * DC + tid;
    const int lane = tid & 63;

    // ---- issue x loads first ----
    const int b0 = bg * TB;
    const float* xp = x + (size_t)b0 * D_SZ + d;
    float xv[TB];
    #pragma unroll
    for (int q = 0; q < TB; ++q) xv[q] = xp[(size_t)q * D_SZ];

    // ---- coef registers (6 coalesced float4 loads) ----
    float4 P0 = effp4[0*D_SZ + d], P1 = effp4[1*D_SZ + d], P2 = effp4[2*D_SZ + d],
           P3 = effp4[3*D_SZ + d], P4 = effp4[4*D_SZ + d], P5 = effp4[5*D_SZ + d];
    const float cp[24] = {P0.x,P0.y,P0.z,P0.w, P1.x,P1.y,P1.z,P1.w,
                          P2.x,P2.y,P2.z,P2.w, P3.x,P3.y,P3.z,P3.w,
                          P4.x,P4.y,P4.z,P4.w, P5.x,P5.y,P5.z,P5.w};
    const float4 eb = effb[d];
    const float ebv[3] = {eb.x, eb.y, eb.z};
    const float g3   = grid[3];                     // -1
    const float invh = 1.0f / (grid[4] - grid[3]);  // 2.5

    #pragma unroll
    for (int q = 0; q < TB; ++q) {
        float X  = xv[q];
        float u  = (X - g3) * invh;                 // in [0,5)
        float u2 = u*u, u3 = u2*u;
        float e   = __expf(-X);
        float sil = X * __builtin_amdgcn_rcpf(1.0f + e);
        float r1 = fmaxf(u - 1.0f, 0.0f), r13 = r1*r1*r1;
        float r2 = fmaxf(u - 2.0f, 0.0f), r23 = r2*r2*r2;
        float r3 = fmaxf(u - 3.0f, 0.0f), r33 = r3*r3*r3;
        float r4 = fmaxf(u - 4.0f, 0.0f), r43 = r4*r4*r4;

        float s[3];
        #pragma unroll
        for (int o = 0; o < 3; ++o) {
            float a = fmaf(sil, ebv[o], cp[0*3+o]);
            a = fmaf(cp[1*3+o], u,   a);
            a = fmaf(cp[2*3+o], u2,  a);
            a = fmaf(cp[3*3+o], u3,  a);
            a = fmaf(cp[4*3+o], r13, a);
            a = fmaf(cp[5*3+o], r23, a);
            a = fmaf(cp[6*3+o], r33, a);
            a = fmaf(cp[7*3+o], r43, a);
            s[o] = group16_sum(a);
        }
        if ((lane & 15) == 15) {
            int g = tid >> 4;              // 0..15 unique per writer
            tl[(q*16 + g)*3 + 0] = s[0];
            tl[(q*16 + g)*3 + 1] = s[1];
            tl[(q*16 + g)*3 + 2] = s[2];
        }
    }

    __syncthreads();
    if (tid < TB*3) {
        int q = tid / 3, o = tid % 3;
        float s = 0.0f;
        #pragma unroll
        for (int g = 0; g < 16; ++g) s += tl[(q*16 + g)*3 + o];
        partial[((size_t)dc * B_SZ + (b0 + q))*3 + o] = s;
    }
}

// ---------------------------------------------------------------------------
__global__ __launch_bounds__(256) void reduce_partials(
    const float* __restrict__ partial, float* __restrict__ out)
{
    int i = blockIdx.x * 256 + threadIdx.x;
    if (i >= B_SZ * 3) return;
    float s = 0.0f;
    #pragma unroll
    for (int c = 0; c < NC; ++c) s += partial[(size_t)c * B_SZ * 3 + i];
    out[i] = s;
}

// ---------------------------------------------------------------------------
// Fallback (no workspace): block per b, raw arrays. Slower but correct.
__global__ __launch_bounds__(256) void kan_fallback(
    const float* __restrict__ x, const float* __restrict__ grid,
    const float* __restrict__ coef, const float* __restrict__ sb,
    const float* __restrict__ ssp,  const float* __restrict__ mask,
    float* __restrict__ out)
{
    __shared__ float red[3][4];
    int b = blockIdx.x, tid = threadIdx.x;
    float g3 = grid[3], invh = 1.0f / (grid[4] - grid[3]);
    float acc[3] = {0.f, 0.f, 0.f};
    for (int i = 0; i < D_SZ / 256; ++i) {
        int d = i * 256 + tid;
        float xv = x[(size_t)b * D_SZ + d];
        float u  = (xv - g3) * invh;
        float cfl = floorf(u);
        cfl = fminf(fmaxf(cfl, 0.0f), 4.0f);
        int  cell = (int)cfl;
        float t  = u - cfl;
        float t2 = t * t, t3 = t2 * t;
        float omt = 1.0f - t;
        float w0 = omt*omt*omt * (1.0f/6.0f);
        float w1 = (3.0f*t3 - 6.0f*t2 + 4.0f) * (1.0f/6.0f);
        float w2 = (-3.0f*t3 + 3.0f*t2 + 3.0f*t + 1.0f) * (1.0f/6.0f);
        float w3 = t3 * (1.0f/6.0f);
        float sil = xv / (1.0f + __expf(-xv));
        #pragma unroll
        for (int o = 0; o < 3; ++o) {
            const float* cp = &coef[(d*3 + o) * 8 + cell];
            float s = w0*cp[0] + w1*cp[1] + w2*cp[2] + w3*cp[3];
            float m = mask[d*3 + o];
            acc[o] += s * ssp[d*3 + o] * m + sil * sb[d*3 + o] * m;
        }
    }
    int lane = tid & 63, wv = tid >> 6;
    #pragma unroll
    for (int o = 0; o < 3; ++o) {
        float v = acc[o];
        #pragma unroll
        for (int off = 32; off >= 1; off >>= 1) v += __shfl_down(v, off, 64);
        if (lane == 0) red[o][wv] = v;
    }
    __syncthreads();
    if (tid < 3) {
        float s = red[tid][0] + red[tid][1] + red[tid][2] + red[tid][3];
        out[b * 3 + tid] = s;
    }
}

// ---------------------------------------------------------------------------
extern "C" void kernel_launch(void* const* d_in, const int* in_sizes, int n_in,
                              void* d_out, int out_size, void* d_ws, size_t ws_size,
                              hipStream_t stream)
{
    const float* x    = (const float*)d_in[0];
    const float* grid = (const float*)d_in[4];
    const float* coef = (const float*)d_in[5];
    const float* sb   = (const float*)d_in[6];
    const float* ssp  = (const float*)d_in[7];
    const float* mask = (const float*)d_in[8];
    float* out = (float*)d_out;

    size_t need = (size_t)WS_EFFP_BYTES + WS_EFFB_BYTES + WS_PART_BYTES;
    if (ws_size >= need) {
        float4* effp4   = (float4*)d_ws;
        float4* effb    = (float4*)((char*)d_ws + WS_EFFP_BYTES);
        float*  partial = (float*)((char*)d_ws + WS_EFFP_BYTES + WS_EFFB_BYTES);

        precompute_pow<<<D_SZ/256, 256, 0, stream>>>(coef, sb, ssp, mask, effp4, effb);
        dim3 g(NBG, NC);
        kan_main<<<g, 256, 0, stream>>>(x, effp4, effb, grid, partial);
        reduce_partials<<<(B_SZ*3 + 255)/256, 256, 0, stream>>>(partial, out);
    } else {
        kan_fallback<<<B_SZ, 256, 0, stream>>>(x, grid, coef, sb, ssp, mask, out);
    }
}